// Round 1
// baseline (192.909 us; speedup 1.0000x reference)
//
#include <hip/hip_runtime.h>
#include <stdint.h>

#define EMBED 384
#define NHEAD 6
#define HSZ   64
#define BATCH 32
#define SEQ   768
#define MROWS (BATCH * SEQ)   // 24576

typedef __bf16 bf16x8 __attribute__((ext_vector_type(8)));
typedef float  f32x4  __attribute__((ext_vector_type(4)));

__device__ inline unsigned short f2bf(float f) {
  union { float f; uint32_t u; } c; c.f = f;
  return (unsigned short)((c.u + 0x7FFFu + ((c.u >> 16) & 1u)) >> 16);
}

// ---------------- fp32 -> bf16 convert (weights only) ----------------
__global__ __launch_bounds__(256) void cvt4(const float* __restrict__ src,
                                            unsigned short* __restrict__ dst, int n) {
  int i = (blockIdx.x * 256 + threadIdx.x) * 4;
  if (i < n) {
    float4 v = *reinterpret_cast<const float4*>(src + i);
    ushort4 o;
    o.x = f2bf(v.x); o.y = f2bf(v.y); o.z = f2bf(v.z); o.w = f2bf(v.w);
    *reinterpret_cast<ushort4*>(dst + i) = o;
  }
}

// ---------------- GEMM: C[m,n] = sum_k A[m,k] * B[n,k]  (B stored [N][K]) ----
// MODE 0: A fp32 (converted during staging), epilogue scatters Q/K/V bf16
// MODE 1: A bf16, epilogue writes fp32 + bias
template <int MODE>
__global__ __launch_bounds__(256) void gemm_bt(
    const void* __restrict__ Ap,
    const unsigned short* __restrict__ Bw,
    unsigned short* __restrict__ Qb,
    unsigned short* __restrict__ Kb,
    unsigned short* __restrict__ Vb,
    float* __restrict__ Co,
    const float* __restrict__ bias) {
  __shared__ __align__(16) short At[128 * 64];
  __shared__ __align__(16) short Bt[128 * 64];
  const int tid = threadIdx.x;
  const int lane = tid & 63;
  const int w = tid >> 6;
  const int wm = w >> 1, wn = w & 1;          // 2x2 waves, 64x64 each
  const int m0 = blockIdx.x * 128, n0 = blockIdx.y * 128;
  const int l15 = lane & 15, lg = lane >> 4;
  char* Ac = (char*)At;
  char* Bc = (char*)Bt;

  f32x4 acc[4][4];
#pragma unroll
  for (int i = 0; i < 4; ++i)
#pragma unroll
    for (int j = 0; j < 4; ++j) acc[i][j] = f32x4{0.f, 0.f, 0.f, 0.f};

#pragma unroll 1
  for (int kt = 0; kt < 6; ++kt) {
    const int k0 = kt * 64;
    __syncthreads();
    // stage A,B tiles: [128 rows][64 k] bf16, swizzle: 16B-unit ^= (row&7)
#pragma unroll
    for (int j = 0; j < 4; ++j) {
      const int u = j * 256 + tid;             // 0..1023 16B-units
      const int row = u >> 3, un = u & 7;
      const int dst = row * 128 + ((un ^ (row & 7)) * 16);
      if (MODE == 0) {
        const float* A = (const float*)Ap;
        const float4* g =
            (const float4*)(A + (size_t)(m0 + row) * EMBED + k0 + un * 8);
        float4 v0 = g[0], v1 = g[1];
        union { int4 i4; unsigned short s[8]; } pk;
        pk.s[0] = f2bf(v0.x); pk.s[1] = f2bf(v0.y);
        pk.s[2] = f2bf(v0.z); pk.s[3] = f2bf(v0.w);
        pk.s[4] = f2bf(v1.x); pk.s[5] = f2bf(v1.y);
        pk.s[6] = f2bf(v1.z); pk.s[7] = f2bf(v1.w);
        *(int4*)(Ac + dst) = pk.i4;
      } else {
        const unsigned short* A = (const unsigned short*)Ap;
        int4 v = *(const int4*)(A + (size_t)(m0 + row) * EMBED + k0 + un * 8);
        *(int4*)(Ac + dst) = v;
      }
      int4 vb = *(const int4*)(Bw + (size_t)(n0 + row) * EMBED + k0 + un * 8);
      *(int4*)(Bc + dst) = vb;
    }
    __syncthreads();
#pragma unroll
    for (int kc = 0; kc < 2; ++kc) {
      bf16x8 af[4], bfr[4];
#pragma unroll
      for (int mt = 0; mt < 4; ++mt) {
        const int row = wm * 64 + mt * 16 + l15;
        af[mt] = *(const bf16x8*)(Ac + row * 128 + (((kc * 4 + lg) ^ (row & 7)) * 16));
      }
#pragma unroll
      for (int nt = 0; nt < 4; ++nt) {
        const int row = wn * 64 + nt * 16 + l15;
        bfr[nt] = *(const bf16x8*)(Bc + row * 128 + (((kc * 4 + lg) ^ (row & 7)) * 16));
      }
#pragma unroll
      for (int mt = 0; mt < 4; ++mt)
#pragma unroll
        for (int nt = 0; nt < 4; ++nt)
          acc[mt][nt] = __builtin_amdgcn_mfma_f32_16x16x32_bf16(
              af[mt], bfr[nt], acc[mt][nt], 0, 0, 0);
    }
  }

  // epilogue: C row = (lg*4 + r), col = l15  [verified m89/m91 layout]
#pragma unroll
  for (int mt = 0; mt < 4; ++mt) {
#pragma unroll
    for (int nt = 0; nt < 4; ++nt) {
#pragma unroll
      for (int r = 0; r < 4; ++r) {
        const int m = m0 + wm * 64 + mt * 16 + lg * 4 + r;
        const int n = n0 + wn * 64 + nt * 16 + l15;
        const float v = acc[mt][nt][r];
        if (MODE == 0) {
          const int which = n / EMBED;    // block never straddles (128 | 384)
          const int c = n - which * EMBED;
          const int h = c >> 6, d = c & 63;
          const int b = m / SEQ, t = m - b * SEQ;
          const size_t off = ((size_t)((b * NHEAD + h) * SEQ + t)) * HSZ + d;
          unsigned short* dstp = (which == 0) ? Qb : (which == 1) ? Kb : Vb;
          dstp[off] = f2bf(which == 0 ? v * 0.125f : v);  // fold 1/sqrt(D) into Q (exact)
        } else {
          Co[(size_t)m * EMBED + n] = v + bias[n];
        }
      }
    }
  }
}

// ---------------- flash attention, causal ----------------
// grid (12 q-tiles, 192 bh). 4 waves x 16 q-rows. KV tiles of 64.
__global__ __launch_bounds__(256) void attn(const unsigned short* __restrict__ Qb,
                                            const unsigned short* __restrict__ Kb,
                                            const unsigned short* __restrict__ Vb,
                                            unsigned short* __restrict__ AO) {
  __shared__ __align__(16) short Kt[64 * 64];       // [kv][d] swizzled
  __shared__ __align__(16) short Vt[64 * 64];       // [d][kv] swizzled (transposed)
  __shared__ __align__(16) short Pl[4][16 * 64];    // per-wave P buffer, swizzled
  const int tid = threadIdx.x, lane = tid & 63, w = tid >> 6;
  const int l15 = lane & 15, lg = lane >> 4;
  const int qt = blockIdx.x, bh = blockIdx.y;
  const int q0 = qt * 64;
  const size_t base = (size_t)bh * SEQ * HSZ;
  char* Kc = (char*)Kt;
  char* Vc = (char*)Vt;
  char* pw = (char*)(&Pl[w][0]);

  // Q A-fragments (2 k-chunks of 32), already scaled by 0.125
  bf16x8 qf[2];
#pragma unroll
  for (int kc = 0; kc < 2; ++kc)
    qf[kc] = *(const bf16x8*)(Qb + base + (size_t)(q0 + w * 16 + l15) * HSZ +
                              kc * 32 + lg * 8);

  f32x4 o[4];
#pragma unroll
  for (int nt = 0; nt < 4; ++nt) o[nt] = f32x4{0.f, 0.f, 0.f, 0.f};
  float mrow[4], lrow[4];
#pragma unroll
  for (int r = 0; r < 4; ++r) { mrow[r] = -3.0e38f; lrow[r] = 0.f; }

#pragma unroll 1
  for (int kt = 0; kt <= qt; ++kt) {
    const int kv0 = kt * 64;
    __syncthreads();   // previous tile fully consumed
    // stage K tile [kv][d], swizzled
#pragma unroll
    for (int j = 0; j < 2; ++j) {
      const int u = j * 256 + tid;
      const int row = u >> 3, un = u & 7;
      int4 v = *(const int4*)(Kb + base + (size_t)(kv0 + row) * HSZ + un * 8);
      *(int4*)(Kc + row * 128 + ((un ^ (row & 7)) * 16)) = v;
    }
    // stage V transposed: VT[d][kv], swizzled
#pragma unroll
    for (int j = 0; j < 2; ++j) {
      const int vr = (tid >> 3) + j * 32;   // kv row
      const int seg = tid & 7;              // d segment
      const unsigned short* vp = Vb + base + (size_t)(kv0 + vr) * HSZ + seg * 8;
      ushort4 a0 = *(const ushort4*)(vp);
      ushort4 a1 = *(const ushort4*)(vp + 4);
      unsigned short e[8] = {a0.x, a0.y, a0.z, a0.w, a1.x, a1.y, a1.z, a1.w};
#pragma unroll
      for (int jj = 0; jj < 8; ++jj) {
        const int d = seg * 8 + jj;
        const int un = (vr >> 3) ^ (d & 7);
        ((unsigned short*)(Vc + d * 128 + un * 16))[vr & 7] = e[jj];
      }
    }
    __syncthreads();

    // S = Q K^T  (rows: wave's 16 q-rows, cols: 64 kv)
    f32x4 s[4];
#pragma unroll
    for (int nt = 0; nt < 4; ++nt) s[nt] = f32x4{0.f, 0.f, 0.f, 0.f};
#pragma unroll
    for (int kc = 0; kc < 2; ++kc) {
#pragma unroll
      for (int nt = 0; nt < 4; ++nt) {
        const int row = nt * 16 + l15;
        bf16x8 kf = *(const bf16x8*)(Kc + row * 128 +
                                     (((kc * 4 + lg) ^ (row & 7)) * 16));
        s[nt] = __builtin_amdgcn_mfma_f32_16x16x32_bf16(qf[kc], kf, s[nt], 0, 0, 0);
      }
    }
    // causal mask on diagonal tile
    if (kt == qt) {
#pragma unroll
      for (int nt = 0; nt < 4; ++nt)
#pragma unroll
        for (int r = 0; r < 4; ++r) {
          const int qrow = w * 16 + lg * 4 + r;
          const int col = nt * 16 + l15;
          if (col > qrow) s[nt][r] = -3.0e38f;
        }
    }
    // online softmax (per q-row; 16-lane butterfly over cols)
    float p[4][4];
#pragma unroll
    for (int r = 0; r < 4; ++r) {
      float t = fmaxf(fmaxf(s[0][r], s[1][r]), fmaxf(s[2][r], s[3][r]));
#pragma unroll
      for (int off = 1; off < 16; off <<= 1) t = fmaxf(t, __shfl_xor(t, off, 64));
      const float mn = fmaxf(mrow[r], t);
      const float alpha = __expf(mrow[r] - mn);
      mrow[r] = mn;
      float srow = 0.f;
#pragma unroll
      for (int nt = 0; nt < 4; ++nt) {
        const float e = __expf(s[nt][r] - mn);
        p[nt][r] = e;
        srow += e;
      }
#pragma unroll
      for (int off = 1; off < 16; off <<= 1) srow += __shfl_xor(srow, off, 64);
      lrow[r] = lrow[r] * alpha + srow;
#pragma unroll
      for (int nt = 0; nt < 4; ++nt) o[nt][r] *= alpha;
    }
    // P: C-layout -> A-layout via per-wave swizzled LDS
#pragma unroll
    for (int nt = 0; nt < 4; ++nt)
#pragma unroll
      for (int r = 0; r < 4; ++r) {
        const int row = lg * 4 + r;
        const int col = nt * 16 + l15;
        const int un = (col >> 3) ^ (row & 7);
        ((unsigned short*)(pw + row * 128 + un * 16))[col & 7] = f2bf(p[nt][r]);
      }
    __syncthreads();
    // O += P V
#pragma unroll
    for (int kc = 0; kc < 2; ++kc) {
      const int prow = l15;
      bf16x8 pf = *(const bf16x8*)(pw + prow * 128 +
                                   (((kc * 4 + lg) ^ (prow & 7)) * 16));
#pragma unroll
      for (int nt = 0; nt < 4; ++nt) {
        const int row = nt * 16 + l15;
        bf16x8 vf = *(const bf16x8*)(Vc + row * 128 +
                                     (((kc * 4 + lg) ^ (row & 7)) * 16));
        o[nt] = __builtin_amdgcn_mfma_f32_16x16x32_bf16(pf, vf, o[nt], 0, 0, 0);
      }
    }
  }

  // epilogue: AO[b][t][h*64+d] bf16
  const int b = bh / NHEAD, h = bh - b * NHEAD;
#pragma unroll
  for (int nt = 0; nt < 4; ++nt)
#pragma unroll
    for (int r = 0; r < 4; ++r) {
      const int t = q0 + w * 16 + lg * 4 + r;
      const int col = h * HSZ + nt * 16 + l15;
      const float v = o[nt][r] / lrow[r];
      AO[((size_t)(b * SEQ + t)) * EMBED + col] = f2bf(v);
    }
}

extern "C" void kernel_launch(void* const* d_in, const int* in_sizes, int n_in,
                              void* d_out, int out_size, void* d_ws, size_t ws_size,
                              hipStream_t stream) {
  const float* X  = (const float*)d_in[0];
  const float* Wq = (const float*)d_in[1];
  const float* Wk = (const float*)d_in[2];
  const float* Wv = (const float*)d_in[3];
  const float* Wo = (const float*)d_in[4];
  const float* bo = (const float*)d_in[5];
  float* out = (float*)d_out;

  const size_t NW = (size_t)EMBED * EMBED;   // 147456
  const size_t NX = (size_t)MROWS * EMBED;   // 9437184
  unsigned short* ws    = (unsigned short*)d_ws;
  unsigned short* Wqkvb = ws;                //  3*NW
  unsigned short* Wob   = Wqkvb + 3 * NW;    //  NW
  unsigned short* Qb    = Wob + NW;          //  NX   [B,H,T,D]
  unsigned short* Kb    = Qb + NX;           //  NX
  unsigned short* Vb    = Kb + NX;           //  NX
  unsigned short* AO    = Vb + NX;           //  NX   [B,T,H*D]
  // total: 4*NW + 4*NX ushorts = 76.7 MB of d_ws

  const int wblk = (int)(NW / 4 / 256);      // 144
  cvt4<<<wblk, 256, 0, stream>>>(Wq, Wqkvb, (int)NW);
  cvt4<<<wblk, 256, 0, stream>>>(Wk, Wqkvb + NW, (int)NW);
  cvt4<<<wblk, 256, 0, stream>>>(Wv, Wqkvb + 2 * NW, (int)NW);
  cvt4<<<wblk, 256, 0, stream>>>(Wo, Wob, (int)NW);

  gemm_bt<0><<<dim3(MROWS / 128, (3 * EMBED) / 128), 256, 0, stream>>>(
      X, Wqkvb, Qb, Kb, Vb, nullptr, nullptr);

  attn<<<dim3(SEQ / 64, BATCH * NHEAD), 256, 0, stream>>>(Qb, Kb, Vb, AO);

  gemm_bt<1><<<dim3(MROWS / 128, EMBED / 128), 256, 0, stream>>>(
      AO, Wob, nullptr, nullptr, nullptr, out, bo);
}

// Round 2
// 179.839 us; speedup vs baseline: 1.0727x; 1.0727x over previous
//
#include <hip/hip_runtime.h>
#include <stdint.h>

#define EMBED 384
#define NHEAD 6
#define HSZ   64
#define BATCH 32
#define SEQ   768
#define MROWS (BATCH * SEQ)   // 24576
#define NTILE (SEQ / 64)      // 12

typedef __bf16 bf16x8 __attribute__((ext_vector_type(8)));
typedef float  f32x4  __attribute__((ext_vector_type(4)));

#define GLD16(gp, lp)                                                        \
  __builtin_amdgcn_global_load_lds(                                          \
      (const __attribute__((address_space(1))) void*)(gp),                   \
      (__attribute__((address_space(3))) void*)(lp), 16, 0, 0)

__device__ inline unsigned short f2bf(float f) {
  union { float f; uint32_t u; } c; c.f = f;
  return (unsigned short)((c.u + 0x7FFFu + ((c.u >> 16) & 1u)) >> 16);
}
__device__ inline int swz8p(int row) { return ((row >> 2) ^ row) & 7; }

// ---------------- fp32 -> bf16 converts ----------------
__global__ __launch_bounds__(256) void cvt4(const float* __restrict__ src,
                                            unsigned short* __restrict__ dst, int n) {
  int i = (blockIdx.x * 256 + threadIdx.x) * 4;
  if (i < n) {
    float4 v = *reinterpret_cast<const float4*>(src + i);
    ushort4 o;
    o.x = f2bf(v.x); o.y = f2bf(v.y); o.z = f2bf(v.z); o.w = f2bf(v.w);
    *reinterpret_cast<ushort4*>(dst + i) = o;
  }
}

__global__ __launch_bounds__(256) void cvtW(const float* __restrict__ a,
                                            const float* __restrict__ b,
                                            const float* __restrict__ c,
                                            const float* __restrict__ d,
                                            unsigned short* __restrict__ dst) {
  const int NWc = EMBED * EMBED;
  int i = (blockIdx.x * 256 + threadIdx.x) * 4;
  int wsel = i / NWc, r = i - wsel * NWc;
  const float* s = (wsel == 0) ? a : (wsel == 1) ? b : (wsel == 2) ? c : d;
  float4 v = *reinterpret_cast<const float4*>(s + r);
  ushort4 o;
  o.x = f2bf(v.x); o.y = f2bf(v.y); o.z = f2bf(v.z); o.w = f2bf(v.w);
  *reinterpret_cast<ushort4*>(dst + i) = o;
}

// ---------------- GEMM: C[m,n] = sum_k A[m,k] * B[n,k]  (B stored [N][K]) ----
// A is bf16 [M][384]. MODE 0: epilogue scatters Q/K/V bf16 (Q scaled 0.125).
// MODE 1: epilogue writes fp32 + bias.
template <int MODE>
__global__ __launch_bounds__(256) void gemm_bt(
    const unsigned short* __restrict__ Ab,
    const unsigned short* __restrict__ Bw,
    unsigned short* __restrict__ Qb,
    unsigned short* __restrict__ Kb,
    unsigned short* __restrict__ Vb,
    float* __restrict__ Co,
    const float* __restrict__ bias) {
  __shared__ __align__(16) short At[128 * 64];
  __shared__ __align__(16) short Bt[128 * 64];
  const int tid = threadIdx.x;
  const int lane = tid & 63;
  const int w = tid >> 6;
  const int wm = w >> 1, wn = w & 1;          // 2x2 waves, 64x64 each
  const int m0 = blockIdx.x * 128, n0 = blockIdx.y * 128;
  const int l15 = lane & 15, lg = lane >> 4;
  char* Ac = (char*)At;
  char* Bc = (char*)Bt;

  f32x4 acc[4][4];
#pragma unroll
  for (int i = 0; i < 4; ++i)
#pragma unroll
    for (int j = 0; j < 4; ++j) acc[i][j] = f32x4{0.f, 0.f, 0.f, 0.f};

#pragma unroll 1
  for (int kt = 0; kt < 6; ++kt) {
    const int k0 = kt * 64;
    __syncthreads();
    // async global->LDS, LDS linear dest, pre-swizzled global source
#pragma unroll
    for (int j = 0; j < 4; ++j) {
      const int u = j * 256 + tid;             // 0..1023 16B-units
      const int row = u >> 3, un = u & 7;
      const int sw = (un ^ (row & 7)) * 8;     // shorts
      const int ub = (j * 256 + (tid & ~63)) * 8;  // wave-uniform LDS base (shorts)
      GLD16(Ab + (size_t)(m0 + row) * EMBED + k0 + sw, &At[ub]);
      GLD16(Bw + (size_t)(n0 + row) * EMBED + k0 + sw, &Bt[ub]);
    }
    __syncthreads();
#pragma unroll
    for (int kc = 0; kc < 2; ++kc) {
      bf16x8 af[4], bfr[4];
#pragma unroll
      for (int mt = 0; mt < 4; ++mt) {
        const int row = wm * 64 + mt * 16 + l15;
        af[mt] = *(const bf16x8*)(Ac + row * 128 + (((kc * 4 + lg) ^ (row & 7)) * 16));
      }
#pragma unroll
      for (int nt = 0; nt < 4; ++nt) {
        const int row = wn * 64 + nt * 16 + l15;
        bfr[nt] = *(const bf16x8*)(Bc + row * 128 + (((kc * 4 + lg) ^ (row & 7)) * 16));
      }
#pragma unroll
      for (int mt = 0; mt < 4; ++mt)
#pragma unroll
        for (int nt = 0; nt < 4; ++nt)
          acc[mt][nt] = __builtin_amdgcn_mfma_f32_16x16x32_bf16(
              af[mt], bfr[nt], acc[mt][nt], 0, 0, 0);
    }
  }

  // epilogue: C row = (lg*4 + r), col = l15
#pragma unroll
  for (int mt = 0; mt < 4; ++mt) {
#pragma unroll
    for (int nt = 0; nt < 4; ++nt) {
#pragma unroll
      for (int r = 0; r < 4; ++r) {
        const int m = m0 + wm * 64 + mt * 16 + lg * 4 + r;
        const int n = n0 + wn * 64 + nt * 16 + l15;
        const float v = acc[mt][nt][r];
        if (MODE == 0) {
          const int which = n / EMBED;    // 128-blocks never straddle
          const int c = n - which * EMBED;
          const int h = c >> 6, d = c & 63;
          const int b = m / SEQ, t = m - b * SEQ;
          const size_t off = ((size_t)((b * NHEAD + h) * SEQ + t)) * HSZ + d;
          unsigned short* dstp = (which == 0) ? Qb : (which == 1) ? Kb : Vb;
          dstp[off] = f2bf(which == 0 ? v * 0.125f : v);  // fold 1/sqrt(D) into Q
        } else {
          Co[(size_t)m * EMBED + n] = v + bias[n];
        }
      }
    }
  }
}

// ---------------- flash attention, causal, paired q-tiles ----------------
// grid (6, 192). Block i handles q-tiles {i, 11-i}: uniform 13 tile-computes.
__global__ __launch_bounds__(256) void attn(const unsigned short* __restrict__ Qb,
                                            const unsigned short* __restrict__ Kb,
                                            const unsigned short* __restrict__ Vb,
                                            unsigned short* __restrict__ AO) {
  __shared__ __align__(16) short Kt[64 * 64];       // [kv][d] swizzled (row&7)
  __shared__ __align__(16) short Vt[64 * 64];       // [d][kv] swizzled (d&7)
  __shared__ __align__(16) short Pl[4][16 * 64];    // per-wave P, swizzled (swz8p)
  const int tid = threadIdx.x, lane = tid & 63, w = tid >> 6;
  const int l15 = lane & 15, lg = lane >> 4;
  const int qtA = blockIdx.x, qtB = (NTILE - 1) - qtA;
  const int bh = blockIdx.y;
  const size_t base = (size_t)bh * SEQ * HSZ;
  char* Kc = (char*)Kt;
  char* Vc = (char*)Vt;
  char* pw = (char*)(&Pl[w][0]);

  bf16x8 qfA[2], qfB[2];
#pragma unroll
  for (int kc = 0; kc < 2; ++kc) {
    qfA[kc] = *(const bf16x8*)(Qb + base + (size_t)(qtA * 64 + w * 16 + l15) * HSZ +
                               kc * 32 + lg * 8);
    qfB[kc] = *(const bf16x8*)(Qb + base + (size_t)(qtB * 64 + w * 16 + l15) * HSZ +
                               kc * 32 + lg * 8);
  }

  f32x4 oA[4], oB[4];
  float mA[4], lA[4], mB[4], lB[4];
#pragma unroll
  for (int r = 0; r < 4; ++r) {
    oA[r] = f32x4{0.f, 0.f, 0.f, 0.f}; oB[r] = f32x4{0.f, 0.f, 0.f, 0.f};
    mA[r] = -3.0e38f; lA[r] = 0.f; mB[r] = -3.0e38f; lB[r] = 0.f;
  }

  auto tile = [&](const bf16x8* qf, f32x4* o, float* mr, float* lr, bool diag) {
    f32x4 s[4];
#pragma unroll
    for (int nt = 0; nt < 4; ++nt) s[nt] = f32x4{0.f, 0.f, 0.f, 0.f};
#pragma unroll
    for (int kc = 0; kc < 2; ++kc)
#pragma unroll
      for (int nt = 0; nt < 4; ++nt) {
        const int row = nt * 16 + l15;
        bf16x8 kf = *(const bf16x8*)(Kc + row * 128 +
                                     (((kc * 4 + lg) ^ (row & 7)) * 16));
        s[nt] = __builtin_amdgcn_mfma_f32_16x16x32_bf16(qf[kc], kf, s[nt], 0, 0, 0);
      }
    if (diag) {
#pragma unroll
      for (int nt = 0; nt < 4; ++nt)
#pragma unroll
        for (int r = 0; r < 4; ++r) {
          const int qrow = w * 16 + lg * 4 + r;
          const int col = nt * 16 + l15;
          if (col > qrow) s[nt][r] = -3.0e38f;
        }
    }
    float p[4][4];
#pragma unroll
    for (int r = 0; r < 4; ++r) {
      float t = fmaxf(fmaxf(s[0][r], s[1][r]), fmaxf(s[2][r], s[3][r]));
#pragma unroll
      for (int off = 1; off < 16; off <<= 1) t = fmaxf(t, __shfl_xor(t, off, 64));
      const float mn = fmaxf(mr[r], t);
      const float alpha = __expf(mr[r] - mn);
      mr[r] = mn;
      float srow = 0.f;
#pragma unroll
      for (int nt = 0; nt < 4; ++nt) {
        const float e = __expf(s[nt][r] - mn);
        p[nt][r] = e;
        srow += e;
      }
#pragma unroll
      for (int off = 1; off < 16; off <<= 1) srow += __shfl_xor(srow, off, 64);
      lr[r] = lr[r] * alpha + srow;
#pragma unroll
      for (int nt = 0; nt < 4; ++nt) o[nt][r] *= alpha;
    }
    // P: C-layout -> A-layout via per-wave swizzled LDS (no barrier: wave-local)
#pragma unroll
    for (int nt = 0; nt < 4; ++nt)
#pragma unroll
      for (int r = 0; r < 4; ++r) {
        const int row = lg * 4 + r;
        const int col = nt * 16 + l15;
        const int un = (col >> 3) ^ swz8p(row);
        ((unsigned short*)(pw + row * 128 + un * 16))[col & 7] = f2bf(p[nt][r]);
      }
    asm volatile("" ::: "memory");
#pragma unroll
    for (int kc = 0; kc < 2; ++kc) {
      bf16x8 pf = *(const bf16x8*)(pw + l15 * 128 +
                                   (((kc * 4 + lg) ^ swz8p(l15)) * 16));
#pragma unroll
      for (int nt = 0; nt < 4; ++nt) {
        const int row = nt * 16 + l15;
        bf16x8 vf = *(const bf16x8*)(Vc + row * 128 +
                                     (((kc * 4 + lg) ^ (row & 7)) * 16));
        o[nt] = __builtin_amdgcn_mfma_f32_16x16x32_bf16(pf, vf, o[nt], 0, 0, 0);
      }
    }
  };

#pragma unroll 1
  for (int kt = 0; kt <= qtB; ++kt) {
    const int kv0 = kt * 64;
    __syncthreads();   // previous tile fully consumed
    // stage K tile [kv][d], swizzled, vectorized (conflict-free)
#pragma unroll
    for (int j = 0; j < 2; ++j) {
      const int u = j * 256 + tid;
      const int row = u >> 3, un = u & 7;
      int4 v = *(const int4*)(Kb + base + (size_t)(kv0 + row) * HSZ + un * 8);
      *(int4*)(Kc + row * 128 + ((un ^ (row & 7)) * 16)) = v;
    }
    // stage V transposed via in-register 8x8 bf16 transpose (3-stage butterfly)
#pragma unroll
    for (int j = 0; j < 2; ++j) {
      const int slab = w * 2 + j;             // 8 kv rows per slab
      const int r8 = lane >> 3, c = lane & 7;
      const uint32_t* src = (const uint32_t*)(Vb + base +
                              (size_t)(kv0 + slab * 8 + r8) * HSZ + c * 8);
      uint32_t v0 = src[0], v1 = src[1], v2 = src[2], v3 = src[3];
      // step 0: lane^8 <-> elem bit0
      uint32_t t0 = __shfl_xor(v0, 8), t1 = __shfl_xor(v1, 8);
      uint32_t t2 = __shfl_xor(v2, 8), t3 = __shfl_xor(v3, 8);
      const bool b0 = (lane & 8) != 0;
      v0 = b0 ? ((t0 >> 16) | (v0 & 0xffff0000u)) : ((v0 & 0xffffu) | (t0 << 16));
      v1 = b0 ? ((t1 >> 16) | (v1 & 0xffff0000u)) : ((v1 & 0xffffu) | (t1 << 16));
      v2 = b0 ? ((t2 >> 16) | (v2 & 0xffff0000u)) : ((v2 & 0xffffu) | (t2 << 16));
      v3 = b0 ? ((t3 >> 16) | (v3 & 0xffff0000u)) : ((v3 & 0xffffu) | (t3 << 16));
      // step 1: lane^16 <-> elem bit1
      uint32_t q0 = __shfl_xor(v0, 16), q1 = __shfl_xor(v1, 16);
      uint32_t q2 = __shfl_xor(v2, 16), q3 = __shfl_xor(v3, 16);
      const bool b1 = (lane & 16) != 0;
      uint32_t n0 = b1 ? q1 : v0, n1 = b1 ? v1 : q0;
      uint32_t n2 = b1 ? q3 : v2, n3 = b1 ? v3 : q2;
      // step 2: lane^32 <-> elem bit2
      uint32_t r0 = __shfl_xor(n0, 32), r1 = __shfl_xor(n1, 32);
      uint32_t r2 = __shfl_xor(n2, 32), r3 = __shfl_xor(n3, 32);
      const bool b2 = (lane & 32) != 0;
      v0 = b2 ? r2 : n0; v1 = b2 ? r3 : n1;
      v2 = b2 ? n2 : r0; v3 = b2 ? n3 : r1;
      // lane now holds V^T[d][kv0+slab*8 .. +7], d = c*8 + r8
      const int d = c * 8 + r8;
      int4 st; st.x = (int)v0; st.y = (int)v1; st.z = (int)v2; st.w = (int)v3;
      *(int4*)(Vc + d * 128 + ((slab ^ (d & 7)) * 16)) = st;
    }
    __syncthreads();

    tile(qfB, oB, mB, lB, kt == qtB);
    if (kt <= qtA) tile(qfA, oA, mA, lA, kt == qtA);
  }

  // epilogue: AO[b][t][h*64+d] bf16, both tiles
  const int bq = bh / NHEAD, h = bh - bq * NHEAD;
  float invA[4], invB[4];
#pragma unroll
  for (int r = 0; r < 4; ++r) { invA[r] = 1.f / lA[r]; invB[r] = 1.f / lB[r]; }
#pragma unroll
  for (int nt = 0; nt < 4; ++nt)
#pragma unroll
    for (int r = 0; r < 4; ++r) {
      const int col = h * HSZ + nt * 16 + l15;
      const int rr = w * 16 + lg * 4 + r;
      AO[((size_t)(bq * SEQ + qtA * 64 + rr)) * EMBED + col] = f2bf(oA[nt][r] * invA[r]);
      AO[((size_t)(bq * SEQ + qtB * 64 + rr)) * EMBED + col] = f2bf(oB[nt][r] * invB[r]);
    }
}

extern "C" void kernel_launch(void* const* d_in, const int* in_sizes, int n_in,
                              void* d_out, int out_size, void* d_ws, size_t ws_size,
                              hipStream_t stream) {
  const float* X  = (const float*)d_in[0];
  const float* Wq = (const float*)d_in[1];
  const float* Wk = (const float*)d_in[2];
  const float* Wv = (const float*)d_in[3];
  const float* Wo = (const float*)d_in[4];
  const float* bo = (const float*)d_in[5];
  float* out = (float*)d_out;

  const size_t NW = (size_t)EMBED * EMBED;   // 147456
  const size_t NX = (size_t)MROWS * EMBED;   // 9437184
  unsigned short* ws    = (unsigned short*)d_ws;
  unsigned short* Wqkvb = ws;                // 3*NW
  unsigned short* Wob   = Wqkvb + 3 * NW;    // NW
  unsigned short* XbAO  = Wob + NW;          // NX: Xb (pre-attn) then AO (post-attn)
  unsigned short* Qb    = XbAO + NX;         // NX   [B,H,T,D]
  unsigned short* Kb    = Qb + NX;           // NX
  unsigned short* Vb    = Kb + NX;           // NX
  // total: 4*NW + 4*NX ushorts = 76.7 MB of d_ws

  cvtW<<<(int)(4 * NW / 4 / 256), 256, 0, stream>>>(Wq, Wk, Wv, Wo, Wqkvb);
  cvt4<<<(int)(NX / 4 / 256), 256, 0, stream>>>(X, XbAO, (int)NX);

  gemm_bt<0><<<dim3(MROWS / 128, (3 * EMBED) / 128), 256, 0, stream>>>(
      XbAO, Wqkvb, Qb, Kb, Vb, nullptr, nullptr);

  attn<<<dim3(NTILE / 2, BATCH * NHEAD), 256, 0, stream>>>(Qb, Kb, Vb, XbAO);

  gemm_bt<1><<<dim3(MROWS / 128, EMBED / 128), 256, 0, stream>>>(
      XbAO, Wob, nullptr, nullptr, nullptr, out, bo);
}

// Round 3
// 118.885 us; speedup vs baseline: 1.6226x; 1.5127x over previous
//
#include <hip/hip_runtime.h>
#include <stdint.h>

#define EMBED 384
#define NHEAD 6
#define HSZ   64
#define BATCH 32
#define SEQ   768
#define MROWS (BATCH * SEQ)   // 24576
#define NTILE (SEQ / 64)      // 12

typedef __bf16 bf16x8 __attribute__((ext_vector_type(8)));
typedef float  f32x4  __attribute__((ext_vector_type(4)));

#define GLD16(gp, lp)                                                        \
  __builtin_amdgcn_global_load_lds(                                          \
      (const __attribute__((address_space(1))) void*)(gp),                   \
      (__attribute__((address_space(3))) void*)(lp), 16, 0, 0)

__device__ inline unsigned short f2bf(float f) {
  union { float f; uint32_t u; } c; c.f = f;
  return (unsigned short)((c.u + 0x7FFFu + ((c.u >> 16) & 1u)) >> 16);
}
__device__ inline unsigned short nbf(float f) {   // native RNE convert
  union { __bf16 b; unsigned short s; } c; c.b = (__bf16)f; return c.s;
}
__device__ inline uint32_t pk2(float a, float b) { // -> v_cvt_pk_bf16_f32
  union { __bf16 b[2]; uint32_t u; } c;
  c.b[0] = (__bf16)a; c.b[1] = (__bf16)b; return c.u;
}

// ---------------- fp32 -> bf16 converts ----------------
__global__ __launch_bounds__(256) void cvt4(const float* __restrict__ src,
                                            unsigned short* __restrict__ dst, int n) {
  int i = (blockIdx.x * 256 + threadIdx.x) * 4;
  if (i < n) {
    float4 v = *reinterpret_cast<const float4*>(src + i);
    ushort4 o;
    o.x = f2bf(v.x); o.y = f2bf(v.y); o.z = f2bf(v.z); o.w = f2bf(v.w);
    *reinterpret_cast<ushort4*>(dst + i) = o;
  }
}

__global__ __launch_bounds__(256) void cvtW(const float* __restrict__ a,
                                            const float* __restrict__ b,
                                            const float* __restrict__ c,
                                            const float* __restrict__ d,
                                            unsigned short* __restrict__ dst) {
  const int NWc = EMBED * EMBED;
  int i = (blockIdx.x * 256 + threadIdx.x) * 4;
  int wsel = i / NWc, r = i - wsel * NWc;
  const float* s = (wsel == 0) ? a : (wsel == 1) ? b : (wsel == 2) ? c : d;
  float4 v = *reinterpret_cast<const float4*>(s + r);
  ushort4 o;
  o.x = f2bf(v.x); o.y = f2bf(v.y); o.z = f2bf(v.z); o.w = f2bf(v.w);
  *reinterpret_cast<ushort4*>(dst + i) = o;
}

// ---------------- GEMM: C[m,n] = sum_k A[m,k] * B[n,k]  (B stored [N][K]) ----
// MODE 0: scatters Q/K bf16 (Q scaled 0.125); V written TRANSPOSED to VT[bh][d][t].
// MODE 1: fp32 out + bias.
template <int MODE>
__global__ __launch_bounds__(256) void gemm_bt(
    const unsigned short* __restrict__ Ab,
    const unsigned short* __restrict__ Bw,
    unsigned short* __restrict__ Qb,
    unsigned short* __restrict__ Kb,
    unsigned short* __restrict__ VT,
    float* __restrict__ Co,
    const float* __restrict__ bias) {
  __shared__ __align__(16) short SH[128 * 128];   // staging: A|B halves; epilogue: 128x128
  short* At = SH;
  short* Bt = SH + 128 * 64;
  const int tid = threadIdx.x;
  const int lane = tid & 63;
  const int w = tid >> 6;
  const int wm = w >> 1, wn = w & 1;
  const int m0 = blockIdx.x * 128, n0 = blockIdx.y * 128;
  const int l15 = lane & 15, lg = lane >> 4;
  char* Ac = (char*)At;
  char* Bc = (char*)Bt;
  char* shc = (char*)SH;

  f32x4 acc[4][4];
#pragma unroll
  for (int i = 0; i < 4; ++i)
#pragma unroll
    for (int j = 0; j < 4; ++j) acc[i][j] = f32x4{0.f, 0.f, 0.f, 0.f};

#pragma unroll 1
  for (int kt = 0; kt < 6; ++kt) {
    const int k0 = kt * 64;
    __syncthreads();
#pragma unroll
    for (int j = 0; j < 4; ++j) {
      const int u = j * 256 + tid;
      const int row = u >> 3, un = u & 7;
      const int sw = (un ^ (row & 7)) * 8;
      const int ub = (j * 256 + (tid & ~63)) * 8;
      GLD16(Ab + (size_t)(m0 + row) * EMBED + k0 + sw, &At[ub]);
      GLD16(Bw + (size_t)(n0 + row) * EMBED + k0 + sw, &Bt[ub]);
    }
    __syncthreads();
#pragma unroll
    for (int kc = 0; kc < 2; ++kc) {
      bf16x8 af[4], bfr[4];
#pragma unroll
      for (int mt = 0; mt < 4; ++mt) {
        const int row = wm * 64 + mt * 16 + l15;
        af[mt] = *(const bf16x8*)(Ac + row * 128 + (((kc * 4 + lg) ^ (row & 7)) * 16));
      }
#pragma unroll
      for (int nt = 0; nt < 4; ++nt) {
        const int row = wn * 64 + nt * 16 + l15;
        bfr[nt] = *(const bf16x8*)(Bc + row * 128 + (((kc * 4 + lg) ^ (row & 7)) * 16));
      }
#pragma unroll
      for (int mt = 0; mt < 4; ++mt)
#pragma unroll
        for (int nt = 0; nt < 4; ++nt)
          acc[mt][nt] = __builtin_amdgcn_mfma_f32_16x16x32_bf16(
              af[mt], bfr[nt], acc[mt][nt], 0, 0, 0);
    }
  }

  if (MODE == 0 && n0 >= 768) {
    // ---- V blocks: transpose via LDS, write VT[bh][d][t] coalesced ----
    const int b = m0 / SEQ, t0 = m0 - b * SEQ;
    __syncthreads();
#pragma unroll
    for (int mt = 0; mt < 4; ++mt)
#pragma unroll
      for (int nt = 0; nt < 4; ++nt)
#pragma unroll
        for (int r = 0; r < 4; ++r) {
          const int tl = wm * 64 + mt * 16 + lg * 4 + r;
          const int nl = wn * 64 + nt * 16 + l15;
          *(unsigned short*)(shc + nl * 256 + (((tl >> 3) ^ (nl & 7)) * 16) +
                             (tl & 7) * 2) = nbf(acc[mt][nt][r]);
        }
    __syncthreads();
#pragma unroll
    for (int j = 0; j < 8; ++j) {
      const int u = j * 256 + tid;
      const int row = u >> 4, un = u & 15;
      int4 vv = *(const int4*)(shc + row * 256 + ((un ^ (row & 7)) * 16));
      const int cg = (n0 - 768) + row;
      const int h = cg >> 6, d = cg & 63;
      *(int4*)(VT + ((size_t)(b * NHEAD + h) * HSZ + d) * SEQ + t0 + un * 8) = vv;
    }
    return;
  }

#pragma unroll
  for (int mt = 0; mt < 4; ++mt) {
#pragma unroll
    for (int nt = 0; nt < 4; ++nt) {
#pragma unroll
      for (int r = 0; r < 4; ++r) {
        const int m = m0 + wm * 64 + mt * 16 + lg * 4 + r;
        const int n = n0 + wn * 64 + nt * 16 + l15;
        const float v = acc[mt][nt][r];
        if (MODE == 0) {
          const int which = n / EMBED;   // 0=Q, 1=K here (V handled above)
          const int c = n - which * EMBED;
          const int h = c >> 6, d = c & 63;
          const int b = m / SEQ, t = m - b * SEQ;
          const size_t off = ((size_t)((b * NHEAD + h) * SEQ + t)) * HSZ + d;
          unsigned short* dstp = (which == 0) ? Qb : Kb;
          dstp[off] = nbf(which == 0 ? v * 0.125f : v);
        } else {
          Co[(size_t)m * EMBED + n] = v + bias[n];
        }
      }
    }
  }
}

// ---------------- flash attention, causal, paired q-tiles, swapped operands --
// grid (8, 144): bh = (by/6)*8+bx groups same-bh blocks on one XCD.
__global__ __launch_bounds__(256, 3) void attn(const unsigned short* __restrict__ Qb,
                                               const unsigned short* __restrict__ Kb,
                                               const unsigned short* __restrict__ VT,
                                               unsigned short* __restrict__ AO) {
  __shared__ __align__(16) short Kt[2][64 * 64];   // [kv][d] swizzled, dbuf
  __shared__ __align__(16) short Vt[2][64 * 64];   // [d][kv] swizzled, dbuf
  __shared__ __align__(16) short Pl[4][16 * 64];   // per-wave P[q][kv] swizzled
  const int tid = threadIdx.x, lane = tid & 63, w = tid >> 6;
  const int l15 = lane & 15, lg = lane >> 4;
  const int bh = (blockIdx.y / 6) * 8 + blockIdx.x;
  const int qtA = blockIdx.y % 6, qtB = (NTILE - 1) - qtA;
  const size_t base = (size_t)bh * SEQ * HSZ;      // Qb/Kb [bh][t][d]
  char* pw = (char*)(&Pl[w][0]);

  bf16x8 qfA[2], qfB[2];
#pragma unroll
  for (int kc = 0; kc < 2; ++kc) {
    qfA[kc] = *(const bf16x8*)(Qb + base + (size_t)(qtA * 64 + w * 16 + l15) * HSZ +
                               kc * 32 + lg * 8);
    qfB[kc] = *(const bf16x8*)(Qb + base + (size_t)(qtB * 64 + w * 16 + l15) * HSZ +
                               kc * 32 + lg * 8);
  }

  f32x4 oA[4], oB[4];
  float mA = -3.0e38f, lA = 0.f, mB = -3.0e38f, lB = 0.f;
#pragma unroll
  for (int nt = 0; nt < 4; ++nt) {
    oA[nt] = f32x4{0.f, 0.f, 0.f, 0.f};
    oB[nt] = f32x4{0.f, 0.f, 0.f, 0.f};
  }

  auto stage = [&](int kt, int buf) {
#pragma unroll
    for (int j = 0; j < 2; ++j) {
      const int u = j * 256 + tid;
      const int row = u >> 3, un = u & 7;
      const int sw = (un ^ (row & 7)) * 8;
      const int ub = (j * 256 + (tid & ~63)) * 8;
      GLD16(Kb + base + (size_t)(kt * 64 + row) * HSZ + sw, &Kt[buf][ub]);
      GLD16(VT + base + (size_t)row * SEQ + kt * 64 + sw, &Vt[buf][ub]);
    }
  };

  // tile: S^T = mfma(K,Q); per-lane softmax (lane owns q=l15); O^T += mfma(V^T,P)
  auto tile = [&](const bf16x8* qf, const bf16x8 kf[2][4], const char* Vc,
                  f32x4* o, float& m, float& l, bool diag) {
    f32x4 s[4];
#pragma unroll
    for (int nt = 0; nt < 4; ++nt) s[nt] = f32x4{0.f, 0.f, 0.f, 0.f};
    __builtin_amdgcn_s_setprio(1);
#pragma unroll
    for (int kc = 0; kc < 2; ++kc)
#pragma unroll
      for (int nt = 0; nt < 4; ++nt)
        s[nt] = __builtin_amdgcn_mfma_f32_16x16x32_bf16(kf[kc][nt], qf[kc], s[nt],
                                                        0, 0, 0);
    __builtin_amdgcn_s_setprio(0);
    if (diag) {
#pragma unroll
      for (int nt = 0; nt < 4; ++nt)
#pragma unroll
        for (int r = 0; r < 4; ++r)
          if (nt * 16 + lg * 4 + r > w * 16 + l15) s[nt][r] = -3.0e38f;
    }
    float mx = s[0][0];
#pragma unroll
    for (int nt = 0; nt < 4; ++nt)
#pragma unroll
      for (int r = 0; r < 4; ++r) mx = fmaxf(mx, s[nt][r]);
    mx = fmaxf(mx, __shfl_xor(mx, 16, 64));
    mx = fmaxf(mx, __shfl_xor(mx, 32, 64));
    const float mn = fmaxf(m, mx);
    const float alpha = __expf(m - mn);
    m = mn;
    float srow = 0.f;
#pragma unroll
    for (int nt = 0; nt < 4; ++nt)
#pragma unroll
      for (int r = 0; r < 4; ++r) {
        const float e = __expf(s[nt][r] - mn);
        s[nt][r] = e;
        srow += e;
      }
    srow += __shfl_xor(srow, 16, 64);
    srow += __shfl_xor(srow, 32, 64);
    l = l * alpha + srow;
#pragma unroll
    for (int nt = 0; nt < 4; ++nt) o[nt] *= alpha;
    // P[q=l15][kv] -> LDS (b64 swizzled writes), packed bf16
#pragma unroll
    for (int nt = 0; nt < 4; ++nt) {
      const int kv = nt * 16 + lg * 4;
      int2 pv;
      pv.x = (int)pk2(s[nt][0], s[nt][1]);
      pv.y = (int)pk2(s[nt][2], s[nt][3]);
      *(int2*)(pw + l15 * 128 + (((kv >> 3) ^ (l15 & 7)) * 16) + (kv & 7) * 2) = pv;
    }
    asm volatile("" ::: "memory");
    bf16x8 pf[2];
#pragma unroll
    for (int kc = 0; kc < 2; ++kc)
      pf[kc] = *(const bf16x8*)(pw + l15 * 128 + (((kc * 4 + lg) ^ (l15 & 7)) * 16));
    __builtin_amdgcn_s_setprio(1);
#pragma unroll
    for (int kc = 0; kc < 2; ++kc)
#pragma unroll
      for (int nt = 0; nt < 4; ++nt) {
        const int row = nt * 16 + l15;
        bf16x8 vf = *(const bf16x8*)(Vc + row * 128 +
                                     (((kc * 4 + lg) ^ (row & 7)) * 16));
        o[nt] = __builtin_amdgcn_mfma_f32_16x16x32_bf16(vf, pf[kc], o[nt], 0, 0, 0);
      }
    __builtin_amdgcn_s_setprio(0);
  };

  stage(0, 0);
  int cur = 0;
#pragma unroll 1
  for (int kt = 0; kt <= qtB; ++kt) {
    __syncthreads();                        // buf[cur] staged; buf[cur^1] free
    if (kt < qtB) stage(kt + 1, cur ^ 1);   // loads fly under compute
    const char* Kc = (const char*)Kt[cur];
    const char* Vc = (const char*)Vt[cur];
    bf16x8 kf[2][4];
#pragma unroll
    for (int kc = 0; kc < 2; ++kc)
#pragma unroll
      for (int nt = 0; nt < 4; ++nt) {
        const int row = nt * 16 + l15;
        kf[kc][nt] = *(const bf16x8*)(Kc + row * 128 +
                                      (((kc * 4 + lg) ^ (row & 7)) * 16));
      }
    tile(qfB, kf, Vc, oB, mB, lB, kt == qtB);
    if (kt <= qtA) tile(qfA, kf, Vc, oA, mA, lA, kt == qtA);
    cur ^= 1;
  }

  // epilogue: lane holds O[q=l15][d=nt*16+lg*4+r]; ushort4 stores
  const int bq = bh / NHEAD, h = bh - bq * NHEAD;
  const float invA = 1.f / lA, invB = 1.f / lB;
#pragma unroll
  for (int nt = 0; nt < 4; ++nt) {
    ushort4 sa, sb;
    sa.x = nbf(oA[nt][0] * invA); sa.y = nbf(oA[nt][1] * invA);
    sa.z = nbf(oA[nt][2] * invA); sa.w = nbf(oA[nt][3] * invA);
    sb.x = nbf(oB[nt][0] * invB); sb.y = nbf(oB[nt][1] * invB);
    sb.z = nbf(oB[nt][2] * invB); sb.w = nbf(oB[nt][3] * invB);
    const int col = h * HSZ + nt * 16 + lg * 4;
    *(ushort4*)(AO + ((size_t)(bq * SEQ + qtA * 64 + w * 16 + l15)) * EMBED + col) = sa;
    *(ushort4*)(AO + ((size_t)(bq * SEQ + qtB * 64 + w * 16 + l15)) * EMBED + col) = sb;
  }
}

extern "C" void kernel_launch(void* const* d_in, const int* in_sizes, int n_in,
                              void* d_out, int out_size, void* d_ws, size_t ws_size,
                              hipStream_t stream) {
  const float* X  = (const float*)d_in[0];
  const float* Wq = (const float*)d_in[1];
  const float* Wk = (const float*)d_in[2];
  const float* Wv = (const float*)d_in[3];
  const float* Wo = (const float*)d_in[4];
  const float* bo = (const float*)d_in[5];
  float* out = (float*)d_out;

  const size_t NW = (size_t)EMBED * EMBED;   // 147456
  const size_t NX = (size_t)MROWS * EMBED;   // 9437184
  unsigned short* ws    = (unsigned short*)d_ws;
  unsigned short* Wqkvb = ws;                // 3*NW
  unsigned short* Wob   = Wqkvb + 3 * NW;    // NW
  unsigned short* XbAO  = Wob + NW;          // NX: Xb (pre-attn) then AO
  unsigned short* Qb    = XbAO + NX;         // NX   [B,H,T,D]
  unsigned short* Kb    = Qb + NX;           // NX   [B,H,T,D]
  unsigned short* VTb   = Kb + NX;           // NX   [B,H,D,T]  (transposed V)
  // total: 4*NW + 4*NX ushorts = 76.7 MB of d_ws

  cvtW<<<(int)(4 * NW / 4 / 256), 256, 0, stream>>>(Wq, Wk, Wv, Wo, Wqkvb);
  cvt4<<<(int)(NX / 4 / 256), 256, 0, stream>>>(X, XbAO, (int)NX);

  gemm_bt<0><<<dim3(MROWS / 128, (3 * EMBED) / 128), 256, 0, stream>>>(
      XbAO, Wqkvb, Qb, Kb, VTb, nullptr, nullptr);

  attn<<<dim3(8, 144), 256, 0, stream>>>(Qb, Kb, VTb, XbAO);

  gemm_bt<1><<<dim3(MROWS / 128, EMBED / 128), 256, 0, stream>>>(
      XbAO, Wob, nullptr, nullptr, nullptr, out, bo);
}

// Round 4
// 118.848 us; speedup vs baseline: 1.6232x; 1.0003x over previous
//
#include <hip/hip_runtime.h>
#include <stdint.h>

#define EMBED 384
#define NHEAD 6
#define HSZ   64
#define BATCH 32
#define SEQ   768
#define MROWS (BATCH * SEQ)   // 24576
#define NTILE (SEQ / 64)      // 12

typedef __bf16 bf16x8 __attribute__((ext_vector_type(8)));
typedef float  f32x4  __attribute__((ext_vector_type(4)));

#define GLD16(gp, lp)                                                        \
  __builtin_amdgcn_global_load_lds(                                          \
      (const __attribute__((address_space(1))) void*)(gp),                   \
      (__attribute__((address_space(3))) void*)(lp), 16, 0, 0)

#define QSCALE 0.18033688011112042f   /* 0.125 * log2(e): exp2-domain scores */

__device__ inline unsigned short nbf(float f) {   // native RNE convert
  union { __bf16 b; unsigned short s; } c; c.b = (__bf16)f; return c.s;
}
__device__ inline uint32_t pk2(float a, float b) { // -> v_cvt_pk_bf16_f32
  union { __bf16 b[2]; uint32_t u; } c;
  c.b[0] = (__bf16)a; c.b[1] = (__bf16)b; return c.u;
}

// ---------------- fused fp32 -> bf16 convert: X then Wq|Wk|Wv|Wo ------------
__global__ __launch_bounds__(256) void cvtAll(const float* __restrict__ X,
                                              const float* __restrict__ Wq,
                                              const float* __restrict__ Wk,
                                              const float* __restrict__ Wv,
                                              const float* __restrict__ Wo,
                                              unsigned short* __restrict__ dstW,
                                              unsigned short* __restrict__ dstX) {
  const int NX = MROWS * EMBED, NW = EMBED * EMBED;
  int i = (blockIdx.x * 256 + threadIdx.x) * 4;
  const float* src;
  unsigned short* dst;
  if (i < NX) {
    src = X + i; dst = dstX + i;
  } else {
    int j = i - NX;
    int wsel = j / NW, r = j - wsel * NW;
    src = ((wsel == 0) ? Wq : (wsel == 1) ? Wk : (wsel == 2) ? Wv : Wo) + r;
    dst = dstW + j;
  }
  float4 v = *reinterpret_cast<const float4*>(src);
  uint2 o;
  o.x = pk2(v.x, v.y); o.y = pk2(v.z, v.w);
  *reinterpret_cast<uint2*>(dst) = o;
}

// ---------------- GEMM: C[m,n] = sum_k A[m,k] * B[n,k]  (B stored [N][K]) ----
// MODE 0: scatters Q/K bf16 (Q scaled by QSCALE); V written transposed VT[bh][d][t].
// MODE 1: fp32 out + bias.
template <int MODE>
__global__ __launch_bounds__(256) void gemm_bt(
    const unsigned short* __restrict__ Ab,
    const unsigned short* __restrict__ Bw,
    unsigned short* __restrict__ Qb,
    unsigned short* __restrict__ Kb,
    unsigned short* __restrict__ VT,
    float* __restrict__ Co,
    const float* __restrict__ bias) {
  __shared__ __align__(16) short SH[128 * 128];   // staging A|B; epilogue 128x128
  short* At = SH;
  short* Bt = SH + 128 * 64;
  const int tid = threadIdx.x;
  const int lane = tid & 63;
  const int w = tid >> 6;
  const int wm = w >> 1, wn = w & 1;
  const int m0 = blockIdx.x * 128, n0 = blockIdx.y * 128;
  const int l15 = lane & 15, lg = lane >> 4;
  char* Ac = (char*)At;
  char* Bc = (char*)Bt;
  char* shc = (char*)SH;

  f32x4 acc[4][4];
#pragma unroll
  for (int i = 0; i < 4; ++i)
#pragma unroll
    for (int j = 0; j < 4; ++j) acc[i][j] = f32x4{0.f, 0.f, 0.f, 0.f};

#pragma unroll 1
  for (int kt = 0; kt < 6; ++kt) {
    const int k0 = kt * 64;
    __syncthreads();
#pragma unroll
    for (int j = 0; j < 4; ++j) {
      const int u = j * 256 + tid;
      const int row = u >> 3, un = u & 7;
      const int sw = (un ^ (row & 7)) * 8;
      const int ub = (j * 256 + (tid & ~63)) * 8;
      GLD16(Ab + (size_t)(m0 + row) * EMBED + k0 + sw, &At[ub]);
      GLD16(Bw + (size_t)(n0 + row) * EMBED + k0 + sw, &Bt[ub]);
    }
    __syncthreads();
#pragma unroll
    for (int kc = 0; kc < 2; ++kc) {
      bf16x8 af[4], bfr[4];
#pragma unroll
      for (int mt = 0; mt < 4; ++mt) {
        const int row = wm * 64 + mt * 16 + l15;
        af[mt] = *(const bf16x8*)(Ac + row * 128 + (((kc * 4 + lg) ^ (row & 7)) * 16));
      }
#pragma unroll
      for (int nt = 0; nt < 4; ++nt) {
        const int row = wn * 64 + nt * 16 + l15;
        bfr[nt] = *(const bf16x8*)(Bc + row * 128 + (((kc * 4 + lg) ^ (row & 7)) * 16));
      }
#pragma unroll
      for (int mt = 0; mt < 4; ++mt)
#pragma unroll
        for (int nt = 0; nt < 4; ++nt)
          acc[mt][nt] = __builtin_amdgcn_mfma_f32_16x16x32_bf16(
              af[mt], bfr[nt], acc[mt][nt], 0, 0, 0);
    }
  }

  if (MODE == 0 && n0 >= 768) {
    // ---- V blocks: transpose via LDS, write VT[bh][d][t] coalesced ----
    const int b = m0 / SEQ, t0 = m0 - b * SEQ;
    __syncthreads();
#pragma unroll
    for (int mt = 0; mt < 4; ++mt)
#pragma unroll
      for (int nt = 0; nt < 4; ++nt)
#pragma unroll
        for (int r = 0; r < 4; ++r) {
          const int tl = wm * 64 + mt * 16 + lg * 4 + r;
          const int nl = wn * 64 + nt * 16 + l15;
          *(unsigned short*)(shc + nl * 256 + (((tl >> 3) ^ (nl & 7)) * 16) +
                             (tl & 7) * 2) = nbf(acc[mt][nt][r]);
        }
    __syncthreads();
#pragma unroll
    for (int j = 0; j < 8; ++j) {
      const int u = j * 256 + tid;
      const int row = u >> 4, un = u & 15;
      int4 vv = *(const int4*)(shc + row * 256 + ((un ^ (row & 7)) * 16));
      const int cg = (n0 - 768) + row;
      const int h = cg >> 6, d = cg & 63;
      *(int4*)(VT + ((size_t)(b * NHEAD + h) * HSZ + d) * SEQ + t0 + un * 8) = vv;
    }
    return;
  }

#pragma unroll
  for (int mt = 0; mt < 4; ++mt) {
#pragma unroll
    for (int nt = 0; nt < 4; ++nt) {
#pragma unroll
      for (int r = 0; r < 4; ++r) {
        const int m = m0 + wm * 64 + mt * 16 + lg * 4 + r;
        const int n = n0 + wn * 64 + nt * 16 + l15;
        const float v = acc[mt][nt][r];
        if (MODE == 0) {
          const int which = n / EMBED;   // 0=Q, 1=K here (V handled above)
          const int c = n - which * EMBED;
          const int h = c >> 6, d = c & 63;
          const int b = m / SEQ, t = m - b * SEQ;
          const size_t off = ((size_t)((b * NHEAD + h) * SEQ + t)) * HSZ + d;
          unsigned short* dstp = (which == 0) ? Qb : Kb;
          dstp[off] = nbf(which == 0 ? v * QSCALE : v);
        } else {
          Co[(size_t)m * EMBED + n] = v + bias[n];
        }
      }
    }
  }
}

// ---------------- flash attention, causal, paired q-tiles, swapped operands --
// grid (8, 144): bh = (by/6)*8+bx groups same-bh blocks on one XCD.
// Scores arrive pre-scaled by log2(e): softmax in exp2 domain.
__global__ __launch_bounds__(256, 3) void attn(const unsigned short* __restrict__ Qb,
                                               const unsigned short* __restrict__ Kb,
                                               const unsigned short* __restrict__ VT,
                                               unsigned short* __restrict__ AO) {
  __shared__ __align__(16) short Kt[2][64 * 64];   // [kv][d] swizzled, dbuf
  __shared__ __align__(16) short Vt[2][64 * 64];   // [d][kv] swizzled, dbuf
  __shared__ __align__(16) short Pl[4][16 * 64];   // per-wave P[q][kv] swizzled
  const int tid = threadIdx.x, lane = tid & 63, w = tid >> 6;
  const int l15 = lane & 15, lg = lane >> 4;
  const int bh = (blockIdx.y / 6) * 8 + blockIdx.x;
  const int qtA = blockIdx.y % 6, qtB = (NTILE - 1) - qtA;
  const size_t base = (size_t)bh * SEQ * HSZ;      // Qb/Kb [bh][t][d]
  char* pw = (char*)(&Pl[w][0]);

  bf16x8 qfA[2], qfB[2];
#pragma unroll
  for (int kc = 0; kc < 2; ++kc) {
    qfA[kc] = *(const bf16x8*)(Qb + base + (size_t)(qtA * 64 + w * 16 + l15) * HSZ +
                               kc * 32 + lg * 8);
    qfB[kc] = *(const bf16x8*)(Qb + base + (size_t)(qtB * 64 + w * 16 + l15) * HSZ +
                               kc * 32 + lg * 8);
  }

  f32x4 oA[4], oB[4];
  float mA = -3.0e38f, lA = 0.f, mB = -3.0e38f, lB = 0.f;   // l = per-lane partial
#pragma unroll
  for (int nt = 0; nt < 4; ++nt) {
    oA[nt] = f32x4{0.f, 0.f, 0.f, 0.f};
    oB[nt] = f32x4{0.f, 0.f, 0.f, 0.f};
  }

  auto stage = [&](int kt, int buf) {
#pragma unroll
    for (int j = 0; j < 2; ++j) {
      const int u = j * 256 + tid;
      const int row = u >> 3, un = u & 7;
      const int sw = (un ^ (row & 7)) * 8;
      const int ub = (j * 256 + (tid & ~63)) * 8;
      GLD16(Kb + base + (size_t)(kt * 64 + row) * HSZ + sw, &Kt[buf][ub]);
      GLD16(VT + base + (size_t)row * SEQ + kt * 64 + sw, &Vt[buf][ub]);
    }
  };

  bf16x8 kf[2][4], vf[2][4];   // hoisted per staged tile, shared by both q-tiles

  // tile: S^T = mfma(K,Q); lane owns q=l15, 16 kv values; defer-rescale softmax.
  auto tile = [&](const bf16x8* qf, f32x4* o, float& m, float& lp, bool diag) {
    f32x4 s[4];
#pragma unroll
    for (int nt = 0; nt < 4; ++nt) s[nt] = f32x4{0.f, 0.f, 0.f, 0.f};
    __builtin_amdgcn_s_setprio(1);
#pragma unroll
    for (int kc = 0; kc < 2; ++kc)
#pragma unroll
      for (int nt = 0; nt < 4; ++nt)
        s[nt] = __builtin_amdgcn_mfma_f32_16x16x32_bf16(kf[kc][nt], qf[kc], s[nt],
                                                        0, 0, 0);
    __builtin_amdgcn_s_setprio(0);
    if (diag) {
#pragma unroll
      for (int nt = 0; nt < 4; ++nt)
#pragma unroll
        for (int r = 0; r < 4; ++r)
          if (nt * 16 + lg * 4 + r > w * 16 + l15) s[nt][r] = -3.0e38f;
    }
    // row max: max3-friendly tree (per-lane 16 vals), then reduce over lg
    float t0 = fmaxf(fmaxf(fmaxf(s[0][0], s[0][1]), s[0][2]), s[0][3]);
    float t1 = fmaxf(fmaxf(fmaxf(s[1][0], s[1][1]), s[1][2]), s[1][3]);
    float t2 = fmaxf(fmaxf(fmaxf(s[2][0], s[2][1]), s[2][2]), s[2][3]);
    float t3 = fmaxf(fmaxf(fmaxf(s[3][0], s[3][1]), s[3][2]), s[3][3]);
    float mx = fmaxf(fmaxf(t0, t1), fmaxf(t2, t3));
    mx = fmaxf(mx, __shfl_xor(mx, 16, 64));
    mx = fmaxf(mx, __shfl_xor(mx, 32, 64));
    // defer-rescale: only rescale when row max grew by >8 (P bounded by 2^8)
    if (!__all(mx <= m + 8.f)) {
      const float mn = fmaxf(m, mx);
      const float alpha = __builtin_amdgcn_exp2f(m - mn);
      m = mn;
      lp *= alpha;
#pragma unroll
      for (int nt = 0; nt < 4; ++nt) o[nt] *= alpha;
    }
    float srow = 0.f;
#pragma unroll
    for (int nt = 0; nt < 4; ++nt)
#pragma unroll
      for (int r = 0; r < 4; ++r) {
        const float e = __builtin_amdgcn_exp2f(s[nt][r] - m);
        s[nt][r] = e;
        srow += e;
      }
    lp += srow;   // per-lane partial; cross-lane sum deferred to epilogue
    // P[q=l15][kv] -> LDS (b64 swizzled writes), packed bf16
#pragma unroll
    for (int nt = 0; nt < 4; ++nt) {
      const int kv = nt * 16 + lg * 4;
      int2 pv;
      pv.x = (int)pk2(s[nt][0], s[nt][1]);
      pv.y = (int)pk2(s[nt][2], s[nt][3]);
      *(int2*)(pw + l15 * 128 + (((kv >> 3) ^ (l15 & 7)) * 16) + (kv & 7) * 2) = pv;
    }
    asm volatile("" ::: "memory");
    bf16x8 pf[2];
#pragma unroll
    for (int kc = 0; kc < 2; ++kc)
      pf[kc] = *(const bf16x8*)(pw + l15 * 128 + (((kc * 4 + lg) ^ (l15 & 7)) * 16));
    __builtin_amdgcn_s_setprio(1);
#pragma unroll
    for (int kc = 0; kc < 2; ++kc)
#pragma unroll
      for (int nt = 0; nt < 4; ++nt)
        o[nt] = __builtin_amdgcn_mfma_f32_16x16x32_bf16(vf[kc][nt], pf[kc], o[nt],
                                                        0, 0, 0);
    __builtin_amdgcn_s_setprio(0);
  };

  stage(0, 0);
  int cur = 0;
#pragma unroll 1
  for (int kt = 0; kt <= qtB; ++kt) {
    __syncthreads();                        // buf[cur] staged; buf[cur^1] free
    if (kt < qtB) stage(kt + 1, cur ^ 1);   // next-tile loads fly under compute
    const char* Kc = (const char*)Kt[cur];
    const char* Vc = (const char*)Vt[cur];
#pragma unroll
    for (int kc = 0; kc < 2; ++kc)
#pragma unroll
      for (int nt = 0; nt < 4; ++nt) {
        const int row = nt * 16 + l15;
        const int sw = ((kc * 4 + lg) ^ (row & 7)) * 16;
        kf[kc][nt] = *(const bf16x8*)(Kc + row * 128 + sw);
        vf[kc][nt] = *(const bf16x8*)(Vc + row * 128 + sw);
      }
    tile(qfB, oB, mB, lB, kt == qtB);
    if (kt <= qtA) tile(qfA, oA, mA, lA, kt == qtA);
    cur ^= 1;
  }

  // epilogue: finish deferred l-reduction; lane holds O[q=l15][d=nt*16+lg*4+r]
  float ltA = lA, ltB = lB;
  ltA += __shfl_xor(ltA, 16, 64); ltA += __shfl_xor(ltA, 32, 64);
  ltB += __shfl_xor(ltB, 16, 64); ltB += __shfl_xor(ltB, 32, 64);
  const float invA = 1.f / ltA, invB = 1.f / ltB;
  const int bq = bh / NHEAD, h = bh - bq * NHEAD;
#pragma unroll
  for (int nt = 0; nt < 4; ++nt) {
    ushort4 sa, sb;
    sa.x = nbf(oA[nt][0] * invA); sa.y = nbf(oA[nt][1] * invA);
    sa.z = nbf(oA[nt][2] * invA); sa.w = nbf(oA[nt][3] * invA);
    sb.x = nbf(oB[nt][0] * invB); sb.y = nbf(oB[nt][1] * invB);
    sb.z = nbf(oB[nt][2] * invB); sb.w = nbf(oB[nt][3] * invB);
    const int col = h * HSZ + nt * 16 + lg * 4;
    *(ushort4*)(AO + ((size_t)(bq * SEQ + qtA * 64 + w * 16 + l15)) * EMBED + col) = sa;
    *(ushort4*)(AO + ((size_t)(bq * SEQ + qtB * 64 + w * 16 + l15)) * EMBED + col) = sb;
  }
}

extern "C" void kernel_launch(void* const* d_in, const int* in_sizes, int n_in,
                              void* d_out, int out_size, void* d_ws, size_t ws_size,
                              hipStream_t stream) {
  const float* X  = (const float*)d_in[0];
  const float* Wq = (const float*)d_in[1];
  const float* Wk = (const float*)d_in[2];
  const float* Wv = (const float*)d_in[3];
  const float* Wo = (const float*)d_in[4];
  const float* bo = (const float*)d_in[5];
  float* out = (float*)d_out;

  const size_t NW = (size_t)EMBED * EMBED;   // 147456
  const size_t NX = (size_t)MROWS * EMBED;   // 9437184
  unsigned short* ws    = (unsigned short*)d_ws;
  unsigned short* Wqkvb = ws;                // 3*NW
  unsigned short* Wob   = Wqkvb + 3 * NW;    // NW (contiguous after Wqkvb)
  unsigned short* XbAO  = Wob + NW;          // NX: Xb (pre-attn) then AO
  unsigned short* Qb    = XbAO + NX;         // NX   [B,H,T,D]
  unsigned short* Kb    = Qb + NX;           // NX   [B,H,T,D]
  unsigned short* VTb   = Kb + NX;           // NX   [B,H,D,T]  (transposed V)
  // total: 4*NW + 4*NX ushorts = 76.7 MB of d_ws

  cvtAll<<<(int)((NX + 4 * NW) / 4 / 256), 256, 0, stream>>>(
      X, Wq, Wk, Wv, Wo, Wqkvb, XbAO);

  gemm_bt<0><<<dim3(MROWS / 128, (3 * EMBED) / 128), 256, 0, stream>>>(
      XbAO, Wqkvb, Qb, Kb, VTb, nullptr, nullptr);

  attn<<<dim3(8, 144), 256, 0, stream>>>(Qb, Kb, VTb, XbAO);

  gemm_bt<1><<<dim3(MROWS / 128, EMBED / 128), 256, 0, stream>>>(
      XbAO, Wob, nullptr, nullptr, nullptr, out, bo);
}